// Round 1
// baseline (1483.951 us; speedup 1.0000x reference)
//
#include <hip/hip_runtime.h>

#define DD 1024
#define BM 128
#define BDc 64
#define BKc 64

typedef short short8 __attribute__((ext_vector_type(8)));   // 8 bf16 in 4 VGPRs
typedef float f32x4 __attribute__((ext_vector_type(4)));

__device__ __forceinline__ unsigned short f2bf(float f) {
  unsigned int u = __float_as_uint(f);
  unsigned int r = (u + 0x7FFFu + ((u >> 16) & 1u)) >> 16;   // RNE
  return (unsigned short)r;
}
__device__ __forceinline__ float sigm(float x) { return 1.0f / (1.0f + __expf(-x)); }
__device__ __forceinline__ float tanh_fast(float x) {
  float e = __expf(-2.0f * fabsf(x));
  float t = (1.0f - e) / (1.0f + e);
  return copysignf(t, x);
}
__device__ __forceinline__ void gload_lds16(const void* g, void* l) {
  __builtin_amdgcn_global_load_lds((const __attribute__((address_space(1))) void*)g,
                                   (__attribute__((address_space(3))) void*)l, 16, 0, 0);
}

// ---- one-time weight prep: Wcat[4][1024][1024] bf16, bias[4][1024] f32 ----
// g=0: Wih_r+Whh_r ; g=1: Wih_z+Whh_z ; g=2: Wih_n ; g=3: Whh_n
__global__ __launch_bounds__(256) void prep_weights(
    const float* __restrict__ Wih, const float* __restrict__ Whh,
    const float* __restrict__ bih, const float* __restrict__ bhh,
    unsigned short* __restrict__ Wcat, float* __restrict__ bias) {
  int i = blockIdx.x * 256 + threadIdx.x;   // float4 units over 4*D*D/4 = 1048576
  int g = i >> 18;                          // / (D*D/4)
  int rem = i & 262143;
  int n = rem >> 8;                         // row within gate
  int k4 = rem & 255;
  const float4* wih4 = reinterpret_cast<const float4*>(Wih);
  const float4* whh4 = reinterpret_cast<const float4*>(Whh);
  float4 v;
  if (g == 0) {
    size_t idx = (size_t)n * 256 + k4;
    float4 a = wih4[idx], b = whh4[idx];
    v = make_float4(a.x + b.x, a.y + b.y, a.z + b.z, a.w + b.w);
  } else if (g == 1) {
    size_t idx = (size_t)(DD + n) * 256 + k4;
    float4 a = wih4[idx], b = whh4[idx];
    v = make_float4(a.x + b.x, a.y + b.y, a.z + b.z, a.w + b.w);
  } else if (g == 2) {
    size_t idx = (size_t)(2 * DD + n) * 256 + k4;
    v = wih4[idx];
  } else {
    size_t idx = (size_t)(2 * DD + n) * 256 + k4;
    v = whh4[idx];
  }
  ushort4 o = make_ushort4(f2bf(v.x), f2bf(v.y), f2bf(v.z), f2bf(v.w));
  reinterpret_cast<ushort4*>(Wcat)[i] = o;

  if (i < 4 * DD) {
    int bg = i >> 10, bn = i & 1023;
    float bv;
    if (bg == 0)      bv = bih[bn] + bhh[bn];
    else if (bg == 1) bv = bih[DD + bn] + bhh[DD + bn];
    else if (bg == 2) bv = bih[2 * DD + bn];
    else              bv = bhh[2 * DD + bn];
    bias[i] = bv;
  }
}

// ---- per-iteration: error GEMV + bf16 cast of state (single read of state) ----
__global__ __launch_bounds__(256) void error_cast(
    const float* S, const float* __restrict__ We, const float* __restrict__ be,
    unsigned short* __restrict__ Sb, float* __restrict__ err) {
  __shared__ float part[4];
  const int row = blockIdx.x;
  const int t = threadIdx.x;
  float4 v = reinterpret_cast<const float4*>(S + (size_t)row * DD)[t];
  float4 w = reinterpret_cast<const float4*>(We)[t];
  float dot = v.x * w.x + v.y * w.y + v.z * w.z + v.w * w.w;
  ushort4 o = make_ushort4(f2bf(v.x), f2bf(v.y), f2bf(v.z), f2bf(v.w));
  reinterpret_cast<ushort4*>(Sb + (size_t)row * DD)[t] = o;
#pragma unroll
  for (int off = 32; off > 0; off >>= 1) dot += __shfl_xor(dot, off);
  if ((t & 63) == 0) part[t >> 6] = dot;
  __syncthreads();
  if (t == 0) err[row] = sigm(part[0] + part[1] + part[2] + part[3] + be[0]);
}

// ---- fused 4-gate GEMM + GRU epilogue ----
// Block tile: 128 rows x 64 d-cols x 4 gates. 4 waves (2x2), wave tile 64x32/gate.
__global__ __launch_bounds__(256) void gru_fused_gemm(
    const unsigned short* __restrict__ Sb,   // [M][1024] bf16 state
    const unsigned short* __restrict__ Wcat, // [4096][1024] bf16
    const float* __restrict__ bias,          // [4096]
    const float* __restrict__ err,           // [M]
    const float* Sf,                         // [M][1024] f32 h (may alias out)
    float* out, int M) {
  __shared__ alignas(16) unsigned short As[BM * BKc];        // 16 KB
  __shared__ alignas(16) unsigned short Bs[4 * BDc * BKc];   // 32 KB

  // XCD-aware swizzle (nwg divisible by 8), then db-outer/rb-inner decode
  const int nwg = gridDim.x;
  const int bid = blockIdx.x;
  const int swz = (bid & 7) * (nwg >> 3) + (bid >> 3);
  int db, rb;
  if (((M / BM) & 31) == 0) {
    int chunk = swz >> 9;          // groups of 512 = 32 rb x 16 db
    int within = swz & 511;
    db = within >> 5;
    rb = (chunk << 5) + (within & 31);
  } else {
    db = swz & 15;
    rb = swz >> 4;
  }

  const int tid = threadIdx.x;
  const int w = tid >> 6;
  const int lane = tid & 63;
  const int wr = w >> 1, wc = w & 1;

  f32x4 acc[4][4][2];
#pragma unroll
  for (int g = 0; g < 4; ++g)
#pragma unroll
    for (int mi = 0; mi < 4; ++mi)
#pragma unroll
      for (int ni = 0; ni < 2; ++ni)
        acc[g][mi][ni] = f32x4{0.f, 0.f, 0.f, 0.f};

  const int l8 = lane >> 3;        // staging row-in-8
  const int lk = (lane & 7) * 8;   // staging k element offset (16B per lane)
  const unsigned short* Abase = Sb + (size_t)rb * BM * DD;

  for (int kt = 0; kt < DD / BKc; ++kt) {
    const int k0 = kt * BKc;
#pragma unroll
    for (int i = 0; i < 4; ++i) {                 // A: 16 KB, 4 chunks/wave
      int ca = w * 4 + i;
      int row = ca * 8 + l8;
      gload_lds16(Abase + (size_t)row * DD + k0 + lk, &As[ca * 512]);
    }
#pragma unroll
    for (int i = 0; i < 8; ++i) {                 // B: 32 KB, 8 chunks/wave
      int cb = w * 8 + i;
      int row = cb * 8 + l8;                      // 0..255 = g*64 + nl
      int g = row >> 6, nl = row & 63;
      gload_lds16(Wcat + ((size_t)(g * DD + db * BDc + nl)) * DD + k0 + lk,
                  &Bs[cb * 512]);
    }
    __syncthreads();
#pragma unroll
    for (int kk = 0; kk < 2; ++kk) {
      const int kb = kk * 32 + (lane >> 4) * 8;
      short8 af[4];
#pragma unroll
      for (int mi = 0; mi < 4; ++mi) {
        int row = wr * 64 + mi * 16 + (lane & 15);
        af[mi] = *reinterpret_cast<const short8*>(&As[row * BKc + kb]);
      }
#pragma unroll
      for (int g = 0; g < 4; ++g) {
#pragma unroll
        for (int ni = 0; ni < 2; ++ni) {
          int brow = g * 64 + wc * 32 + ni * 16 + (lane & 15);
          short8 bfv = *reinterpret_cast<const short8*>(&Bs[brow * BKc + kb]);
#pragma unroll
          for (int mi = 0; mi < 4; ++mi)
            acc[g][mi][ni] =
                __builtin_amdgcn_mfma_f32_16x16x32_bf16(af[mi], bfv, acc[g][mi][ni], 0, 0, 0);
        }
      }
    }
    __syncthreads();
  }

  // epilogue: r,z,n + out = h + e*(1-z)*(n-h)
  const int mbase = rb * BM + wr * 64;
  const int dbase = db * BDc + wc * 32;
#pragma unroll
  for (int mi = 0; mi < 4; ++mi) {
#pragma unroll
    for (int j = 0; j < 4; ++j) {
      int m = mbase + mi * 16 + ((lane >> 4) << 2) + j;
      float e = err[m];
      const float* hrow = Sf + (size_t)m * DD;
      float* orow = out + (size_t)m * DD;
#pragma unroll
      for (int ni = 0; ni < 2; ++ni) {
        int dg = dbase + ni * 16 + (lane & 15);
        float gr = acc[0][mi][ni][j] + bias[dg];
        float gz = acc[1][mi][ni][j] + bias[DD + dg];
        float gi = acc[2][mi][ni][j] + bias[2 * DD + dg];
        float gh = acc[3][mi][ni][j] + bias[3 * DD + dg];
        float r = sigm(gr);
        float z = sigm(gz);
        float n = tanh_fast(gi + r * gh);
        float h = hrow[dg];
        orow[dg] = h + e * (1.0f - z) * (n - h);
      }
    }
  }
}

extern "C" void kernel_launch(void* const* d_in, const int* in_sizes, int n_in,
                              void* d_out, int out_size, void* d_ws, size_t ws_size,
                              hipStream_t stream) {
  const float* x   = (const float*)d_in[0];
  const float* Wih = (const float*)d_in[1];
  const float* Whh = (const float*)d_in[2];
  const float* bih = (const float*)d_in[3];
  const float* bhh = (const float*)d_in[4];
  const float* We  = (const float*)d_in[5];
  const float* be  = (const float*)d_in[6];
  float* out = (float*)d_out;
  const int M = in_sizes[0] / DD;   // 32768

  char* ws = (char*)d_ws;
  unsigned short* Sb   = (unsigned short*)ws;                              // M*D*2
  unsigned short* Wcat = (unsigned short*)(ws + (size_t)M * DD * 2);       // 8 MB
  float* bias = (float*)(ws + (size_t)M * DD * 2 + (size_t)4 * DD * DD * 2);
  float* err  = (float*)(ws + (size_t)M * DD * 2 + (size_t)4 * DD * DD * 2 + (size_t)4 * DD * 4);

  prep_weights<<<4096, 256, 0, stream>>>(Wih, Whh, bih, bhh, Wcat, bias);

  const int nwg = (M / BM) * (DD / BDc);   // 4096
  const float* S = x;
  for (int it = 0; it < 2; ++it) {
    error_cast<<<M, 256, 0, stream>>>(S, We, be, Sb, err);
    gru_fused_gemm<<<nwg, 256, 0, stream>>>(Sb, Wcat, bias, err, S, out, M);
    S = out;   // iteration 2: in-place update of d_out (element-local read-before-write)
  }
}

// Round 2
// 881.423 us; speedup vs baseline: 1.6836x; 1.6836x over previous
//
#include <hip/hip_runtime.h>

#define DD 1024
#define BM 128
#define BDc 64
#define BKc 64

typedef short short8 __attribute__((ext_vector_type(8)));   // 8 bf16 in 4 VGPRs
typedef float f32x4 __attribute__((ext_vector_type(4)));

__device__ __forceinline__ unsigned short f2bf(float f) {
  unsigned int u = __float_as_uint(f);
  unsigned int r = (u + 0x7FFFu + ((u >> 16) & 1u)) >> 16;   // RNE
  return (unsigned short)r;
}
__device__ __forceinline__ float sigm(float x) { return 1.0f / (1.0f + __expf(-x)); }
__device__ __forceinline__ float tanh_fast(float x) {
  float e = __expf(-2.0f * fabsf(x));
  float t = (1.0f - e) / (1.0f + e);
  return copysignf(t, x);
}
__device__ __forceinline__ void gload_lds16(const void* g, void* l) {
  __builtin_amdgcn_global_load_lds((const __attribute__((address_space(1))) void*)g,
                                   (__attribute__((address_space(3))) void*)l, 16, 0, 0);
}

// ---- one-time weight prep: Wcat[4][1024][1024] bf16, bias[4][1024] f32 ----
// g=0: Wih_r+Whh_r ; g=1: Wih_z+Whh_z ; g=2: Wih_n ; g=3: Whh_n
__global__ __launch_bounds__(256) void prep_weights(
    const float* __restrict__ Wih, const float* __restrict__ Whh,
    const float* __restrict__ bih, const float* __restrict__ bhh,
    unsigned short* __restrict__ Wcat, float* __restrict__ bias) {
  int i = blockIdx.x * 256 + threadIdx.x;   // float4 units over 4*D*D/4 = 1048576
  int g = i >> 18;                          // / (D*D/4)
  int rem = i & 262143;
  int n = rem >> 8;                         // row within gate
  int k4 = rem & 255;
  const float4* wih4 = reinterpret_cast<const float4*>(Wih);
  const float4* whh4 = reinterpret_cast<const float4*>(Whh);
  float4 v;
  if (g == 0) {
    size_t idx = (size_t)n * 256 + k4;
    float4 a = wih4[idx], b = whh4[idx];
    v = make_float4(a.x + b.x, a.y + b.y, a.z + b.z, a.w + b.w);
  } else if (g == 1) {
    size_t idx = (size_t)(DD + n) * 256 + k4;
    float4 a = wih4[idx], b = whh4[idx];
    v = make_float4(a.x + b.x, a.y + b.y, a.z + b.z, a.w + b.w);
  } else if (g == 2) {
    size_t idx = (size_t)(2 * DD + n) * 256 + k4;
    v = wih4[idx];
  } else {
    size_t idx = (size_t)(2 * DD + n) * 256 + k4;
    v = whh4[idx];
  }
  ushort4 o = make_ushort4(f2bf(v.x), f2bf(v.y), f2bf(v.z), f2bf(v.w));
  reinterpret_cast<ushort4*>(Wcat)[i] = o;

  if (i < 4 * DD) {
    int bg = i >> 10, bn = i & 1023;
    float bv;
    if (bg == 0)      bv = bih[bn] + bhh[bn];
    else if (bg == 1) bv = bih[DD + bn] + bhh[DD + bn];
    else if (bg == 2) bv = bih[2 * DD + bn];
    else              bv = bhh[2 * DD + bn];
    bias[i] = bv;
  }
}

// ---- per-iteration: error GEMV + bf16 cast of state (single read of state) ----
__global__ __launch_bounds__(256) void error_cast(
    const float* S, const float* __restrict__ We, const float* __restrict__ be,
    unsigned short* __restrict__ Sb, float* __restrict__ err) {
  __shared__ float part[4];
  const int row = blockIdx.x;
  const int t = threadIdx.x;
  float4 v = reinterpret_cast<const float4*>(S + (size_t)row * DD)[t];
  float4 w = reinterpret_cast<const float4*>(We)[t];
  float dot = v.x * w.x + v.y * w.y + v.z * w.z + v.w * w.w;
  ushort4 o = make_ushort4(f2bf(v.x), f2bf(v.y), f2bf(v.z), f2bf(v.w));
  reinterpret_cast<ushort4*>(Sb + (size_t)row * DD)[t] = o;
#pragma unroll
  for (int off = 32; off > 0; off >>= 1) dot += __shfl_xor(dot, off);
  if ((t & 63) == 0) part[t >> 6] = dot;
  __syncthreads();
  if (t == 0) err[row] = sigm(part[0] + part[1] + part[2] + part[3] + be[0]);
}

// ---- fused 4-gate GEMM + GRU epilogue ----
// Block: 512 thr = 8 waves (2 M x 4 D). Tile: 128 rows x 64 d-cols x 4 gates.
// Wave tile: 64M x 16d x 4g -> acc[4][4] = 64 regs (vs 128 before).
// LDS XOR-swizzle (T2) via pre-swizzled global source + swizzled ds_read.
__global__ __launch_bounds__(512, 4) void gru_fused_gemm(
    const unsigned short* __restrict__ Sb,   // [M][1024] bf16 state
    const unsigned short* __restrict__ Wcat, // [4096][1024] bf16
    const float* __restrict__ bias,          // [4096]
    const float* __restrict__ err,           // [M]
    const float* Sf,                         // [M][1024] f32 h (may alias out)
    float* out, int M) {
  __shared__ alignas(16) unsigned short As[BM * BKc];        // 16 KB
  __shared__ alignas(16) unsigned short Bs[4 * BDc * BKc];   // 32 KB

  // XCD-aware swizzle (nwg divisible by 8), then chunked db/rb decode for L2
  const int nwg = gridDim.x;
  const int bid = blockIdx.x;
  const int swz = (bid & 7) * (nwg >> 3) + (bid >> 3);
  int db, rb;
  if (((M / BM) & 31) == 0) {
    int chunk = swz >> 9;          // groups of 512 = 16 db x 32 rb
    int within = swz & 511;
    db = within >> 5;
    rb = (chunk << 5) + (within & 31);
  } else {
    db = swz & 15;
    rb = swz >> 4;
  }

  const int tid = threadIdx.x;
  const int w = tid >> 6;          // 0..7
  const int lane = tid & 63;
  const int wr = w >> 2, wc = w & 3;   // 2 x 4 wave grid

  f32x4 acc[4][4];
#pragma unroll
  for (int g = 0; g < 4; ++g)
#pragma unroll
    for (int mi = 0; mi < 4; ++mi)
      acc[g][mi] = f32x4{0.f, 0.f, 0.f, 0.f};

  // staging: each wave owns 6 chunks of 8rows x 64k (1 KB each): A: w, w+8; B: w,w+8,w+16,w+24
  const int l8 = lane >> 3;                       // row-in-chunk
  const int lk = ((lane & 7) ^ l8) * 8;           // PRE-SWIZZLED source k offset (involution)
  const unsigned short* Abase = Sb + (size_t)rb * BM * DD;
  const unsigned short* srcA0 = Abase + (size_t)(w * 8 + l8) * DD + lk;
  const unsigned short* srcA1 = Abase + (size_t)((w + 8) * 8 + l8) * DD + lk;
  const unsigned short* srcB[4];
#pragma unroll
  for (int j = 0; j < 4; ++j) {
    int rowb = (w + j * 8) * 8 + l8;              // 0..255 = g*64 + dl
    int g = rowb >> 6, dl = rowb & 63;
    srcB[j] = Wcat + ((size_t)(g * DD + db * BDc + dl)) * DD + lk;
  }
  unsigned short* const dstA0 = As + w * 512;
  unsigned short* const dstA1 = As + (w + 8) * 512;
  unsigned short* const dstB0 = Bs + w * 512;
  unsigned short* const dstB1 = Bs + (w + 8) * 512;
  unsigned short* const dstB2 = Bs + (w + 16) * 512;
  unsigned short* const dstB3 = Bs + (w + 24) * 512;

  const int lrow = lane & 15;
  const int swz_rd = (lane & 7) << 3;             // read-side XOR (shorts)

  for (int kt = 0; kt < DD / BKc; ++kt) {
    const int k0 = kt * BKc;
    gload_lds16(srcA0 + k0, dstA0);
    gload_lds16(srcA1 + k0, dstA1);
    gload_lds16(srcB[0] + k0, dstB0);
    gload_lds16(srcB[1] + k0, dstB1);
    gload_lds16(srcB[2] + k0, dstB2);
    gload_lds16(srcB[3] + k0, dstB3);
    __syncthreads();
#pragma unroll
    for (int kk = 0; kk < 2; ++kk) {
      const int kbs = (kk * 32 + (lane >> 4) * 8) ^ swz_rd;   // swizzled k start
      short8 af[4];
#pragma unroll
      for (int mi = 0; mi < 4; ++mi) {
        int row = wr * 64 + mi * 16 + lrow;       // row&7 == lane&7
        af[mi] = *reinterpret_cast<const short8*>(&As[row * BKc + kbs]);
      }
#pragma unroll
      for (int g = 0; g < 4; ++g) {
        int brow = g * 64 + wc * 16 + lrow;       // brow&7 == lane&7
        short8 bfv = *reinterpret_cast<const short8*>(&Bs[brow * BKc + kbs]);
#pragma unroll
        for (int mi = 0; mi < 4; ++mi)
          acc[g][mi] =
              __builtin_amdgcn_mfma_f32_16x16x32_bf16(af[mi], bfv, acc[g][mi], 0, 0, 0);
      }
    }
    __syncthreads();
  }

  // epilogue: r,z,n + out = h + e*(1-z)*(n-h)
  const int mbase = rb * BM + wr * 64;
  const int dg = db * BDc + wc * 16 + lrow;
  const float b_r = bias[dg];
  const float b_z = bias[DD + dg];
  const float b_i = bias[2 * DD + dg];
  const float b_h = bias[3 * DD + dg];
#pragma unroll
  for (int mi = 0; mi < 4; ++mi) {
#pragma unroll
    for (int j = 0; j < 4; ++j) {
      int m = mbase + mi * 16 + ((lane >> 4) << 2) + j;
      float e = err[m];
      float h = Sf[(size_t)m * DD + dg];
      float r = sigm(acc[0][mi][j] + b_r);
      float z = sigm(acc[1][mi][j] + b_z);
      float n = tanh_fast(acc[2][mi][j] + b_i + r * (acc[3][mi][j] + b_h));
      out[(size_t)m * DD + dg] = h + e * (1.0f - z) * (n - h);
    }
  }
}

extern "C" void kernel_launch(void* const* d_in, const int* in_sizes, int n_in,
                              void* d_out, int out_size, void* d_ws, size_t ws_size,
                              hipStream_t stream) {
  const float* x   = (const float*)d_in[0];
  const float* Wih = (const float*)d_in[1];
  const float* Whh = (const float*)d_in[2];
  const float* bih = (const float*)d_in[3];
  const float* bhh = (const float*)d_in[4];
  const float* We  = (const float*)d_in[5];
  const float* be  = (const float*)d_in[6];
  float* out = (float*)d_out;
  const int M = in_sizes[0] / DD;   // 32768

  char* ws = (char*)d_ws;
  unsigned short* Sb   = (unsigned short*)ws;                              // M*D*2
  unsigned short* Wcat = (unsigned short*)(ws + (size_t)M * DD * 2);       // 8 MB
  float* bias = (float*)(ws + (size_t)M * DD * 2 + (size_t)4 * DD * DD * 2);
  float* err  = (float*)(ws + (size_t)M * DD * 2 + (size_t)4 * DD * DD * 2 + (size_t)4 * DD * 4);

  prep_weights<<<4096, 256, 0, stream>>>(Wih, Whh, bih, bhh, Wcat, bias);

  const int nwg = (M / BM) * (DD / BDc);   // 4096
  const float* S = x;
  for (int it = 0; it < 2; ++it) {
    error_cast<<<M, 256, 0, stream>>>(S, We, be, Sb, err);
    gru_fused_gemm<<<nwg, 512, 0, stream>>>(Sb, Wcat, bias, err, S, out, M);
    S = out;   // iteration 2: in-place update of d_out (element-local read-before-write)
  }
}

// Round 3
// 693.247 us; speedup vs baseline: 2.1406x; 1.2714x over previous
//
#include <hip/hip_runtime.h>

#define DD 1024

typedef short short8 __attribute__((ext_vector_type(8)));   // 8 bf16 in 4 VGPRs
typedef float f32x4 __attribute__((ext_vector_type(4)));

__device__ __forceinline__ unsigned short f2bf(float f) {
  unsigned int u = __float_as_uint(f);
  unsigned int r = (u + 0x7FFFu + ((u >> 16) & 1u)) >> 16;   // RNE
  return (unsigned short)r;
}
__device__ __forceinline__ float sigm(float x) { return 1.0f / (1.0f + __expf(-x)); }
__device__ __forceinline__ float tanh_fast(float x) {
  float e = __expf(-2.0f * fabsf(x));
  float t = (1.0f - e) / (1.0f + e);
  return copysignf(t, x);
}
__device__ __forceinline__ void gload_lds16(const void* g, void* l) {
  __builtin_amdgcn_global_load_lds((const __attribute__((address_space(1))) void*)g,
                                   (__attribute__((address_space(3))) void*)l, 16, 0, 0);
}

// ---- one-time weight prep: Wcat[4][1024][1024] bf16, bias[4][1024] f32 ----
// g=0: Wih_r+Whh_r ; g=1: Wih_z+Whh_z ; g=2: Wih_n ; g=3: Whh_n
__global__ __launch_bounds__(256) void prep_weights(
    const float* __restrict__ Wih, const float* __restrict__ Whh,
    const float* __restrict__ bih, const float* __restrict__ bhh,
    unsigned short* __restrict__ Wcat, float* __restrict__ bias) {
  int i = blockIdx.x * 256 + threadIdx.x;
  int g = i >> 18;
  int rem = i & 262143;
  int n = rem >> 8;
  int k4 = rem & 255;
  const float4* wih4 = reinterpret_cast<const float4*>(Wih);
  const float4* whh4 = reinterpret_cast<const float4*>(Whh);
  float4 v;
  if (g == 0) {
    size_t idx = (size_t)n * 256 + k4;
    float4 a = wih4[idx], b = whh4[idx];
    v = make_float4(a.x + b.x, a.y + b.y, a.z + b.z, a.w + b.w);
  } else if (g == 1) {
    size_t idx = (size_t)(DD + n) * 256 + k4;
    float4 a = wih4[idx], b = whh4[idx];
    v = make_float4(a.x + b.x, a.y + b.y, a.z + b.z, a.w + b.w);
  } else if (g == 2) {
    size_t idx = (size_t)(2 * DD + n) * 256 + k4;
    v = wih4[idx];
  } else {
    size_t idx = (size_t)(2 * DD + n) * 256 + k4;
    v = whh4[idx];
  }
  ushort4 o = make_ushort4(f2bf(v.x), f2bf(v.y), f2bf(v.z), f2bf(v.w));
  reinterpret_cast<ushort4*>(Wcat)[i] = o;

  if (i < 4 * DD) {
    int bg = i >> 10, bn = i & 1023;
    float bv;
    if (bg == 0)      bv = bih[bn] + bhh[bn];
    else if (bg == 1) bv = bih[DD + bn] + bhh[DD + bn];
    else if (bg == 2) bv = bih[2 * DD + bn];
    else              bv = bhh[2 * DD + bn];
    bias[i] = bv;
  }
}

// ---- per-iteration: error GEMV + bf16 cast of state ----
__global__ __launch_bounds__(256) void error_cast(
    const float* S, const float* __restrict__ We, const float* __restrict__ be,
    unsigned short* __restrict__ Sb, float* __restrict__ err) {
  __shared__ float part[4];
  const int row = blockIdx.x;
  const int t = threadIdx.x;
  float4 v = reinterpret_cast<const float4*>(S + (size_t)row * DD)[t];
  float4 w = reinterpret_cast<const float4*>(We)[t];
  float dot = v.x * w.x + v.y * w.y + v.z * w.z + v.w * w.w;
  ushort4 o = make_ushort4(f2bf(v.x), f2bf(v.y), f2bf(v.z), f2bf(v.w));
  reinterpret_cast<ushort4*>(Sb + (size_t)row * DD)[t] = o;
#pragma unroll
  for (int off = 32; off > 0; off >>= 1) dot += __shfl_xor(dot, off);
  if ((t & 63) == 0) part[t >> 6] = dot;
  __syncthreads();
  if (t == 0) err[row] = sigm(part[0] + part[1] + part[2] + part[3] + be[0]);
}

// ---- fused 4-gate GEMM + GRU epilogue, counted-vmcnt 2-slot pipeline ----
// Tile 256M x (4g x 64dg), BK=64, 16 K-tiles. 8 waves (2M x 4N), wave 128x64.
// Per K-tile: vmcnt(8); bar; rd kk0; MFMA32; rd kk1; lgkmcnt(0); bar;
//             stage(t+2) into freed slot; MFMA32.  Loads span barriers.
__global__ __launch_bounds__(512, 2) void gru_fused_gemm(
    const unsigned short* __restrict__ Sb,   // [M][1024] bf16 state
    const unsigned short* __restrict__ Wcat, // [4096][1024] bf16
    const float* __restrict__ bias,          // [4096]
    const float* __restrict__ err,           // [M]
    const float* Sf,                         // [M][1024] f32 h (may alias out)
    float* out, int M) {
  __shared__ alignas(16) unsigned short As[2 * 256 * 64];   // 64 KB (2 slots)
  __shared__ alignas(16) unsigned short Bs[2 * 256 * 64];   // 64 KB (2 slots)

  // XCD swizzle; per-XCD: rb outer, db inner -> A-panel (512 KB) L2-resident
  const int nwg = gridDim.x;
  const int bid = blockIdx.x;
  const int swz = (bid & 7) * (nwg >> 3) + (bid >> 3);
  const int db = swz & 15;
  const int rb = swz >> 4;

  const int tid = threadIdx.x;
  const int w = tid >> 6;          // 0..7
  const int lane = tid & 63;
  const int wr = w >> 2, wc = w & 3;

  // ---- staging setup: 8 chunks/wave (4 A + 4 B), 1 KB each, pre-swizzled src
  const int l8 = lane >> 3;
  const int lkb = ((lane & 7) ^ l8) * 8;          // swizzled k-elem offset
  const unsigned short* srcA[4];
  const unsigned short* srcB[4];
  unsigned short* dstA[4];
  unsigned short* dstB[4];
#pragma unroll
  for (int i = 0; i < 4; ++i) {
    int c = w + i * 8;            // chunk 0..31 (8 rows each)
    int r = c * 8 + l8;           // tile row 0..255
    srcA[i] = Sb + (size_t)(rb * 256 + r) * DD + lkb;
    int wcq = r >> 6, g = (r >> 4) & 3, dgl = r & 15;
    srcB[i] = Wcat + (size_t)(g * DD + db * 64 + wcq * 16 + dgl) * DD + lkb;
    dstA[i] = As + c * 512;       // wave-uniform base (lane*16B appended by HW)
    dstB[i] = Bs + c * 512;
  }

  auto stage = [&](int t) {
    const int slot = (t & 1) * 16384;   // elements
    const int koff = t * 64;
#pragma unroll
    for (int i = 0; i < 4; ++i) gload_lds16(srcA[i] + koff, dstA[i] + slot);
#pragma unroll
    for (int i = 0; i < 4; ++i) gload_lds16(srcB[i] + koff, dstB[i] + slot);
  };

  // ---- read-side addressing
  const int l15 = lane & 15;
  const int g4 = lane >> 4;                        // 0..3
  const int kx = (lane & 7) * 8;                   // XOR swizzle (elements)
  const int arow0 = (wr * 128 + l15) * 64;         // element offsets
  const int brow0 = (wc * 64 + l15) * 64;

  f32x4 acc[8][4];
#pragma unroll
  for (int mi = 0; mi < 8; ++mi)
#pragma unroll
    for (int g = 0; g < 4; ++g) acc[mi][g] = f32x4{0.f, 0.f, 0.f, 0.f};

  stage(0);
  stage(1);

  for (int t = 0; t < 16; ++t) {
    if (t < 15) asm volatile("s_waitcnt vmcnt(8)" ::: "memory");
    else        asm volatile("s_waitcnt vmcnt(0)" ::: "memory");
    __builtin_amdgcn_s_barrier();
    const int sb = (t & 1) * 16384;

    // ---- kk = 0
    short8 a[8], b[4];
    const int k0 = (g4 * 8) ^ kx;
#pragma unroll
    for (int mi = 0; mi < 8; ++mi)
      a[mi] = *reinterpret_cast<const short8*>(&As[sb + arow0 + mi * 1024 + k0]);
#pragma unroll
    for (int g = 0; g < 4; ++g)
      b[g] = *reinterpret_cast<const short8*>(&Bs[sb + brow0 + g * 1024 + k0]);
    __builtin_amdgcn_s_setprio(1);
#pragma unroll
    for (int g = 0; g < 4; ++g)
#pragma unroll
      for (int mi = 0; mi < 8; ++mi)
        acc[mi][g] = __builtin_amdgcn_mfma_f32_16x16x32_bf16(a[mi], b[g], acc[mi][g], 0, 0, 0);
    __builtin_amdgcn_s_setprio(0);

    // ---- kk = 1 reads, then release slot & prefetch t+2 into it
    const int k1 = (32 + g4 * 8) ^ kx;
    short8 a2[8], b2[4];
#pragma unroll
    for (int mi = 0; mi < 8; ++mi)
      a2[mi] = *reinterpret_cast<const short8*>(&As[sb + arow0 + mi * 1024 + k1]);
#pragma unroll
    for (int g = 0; g < 4; ++g)
      b2[g] = *reinterpret_cast<const short8*>(&Bs[sb + brow0 + g * 1024 + k1]);
    asm volatile("s_waitcnt lgkmcnt(0)" ::: "memory");
    __builtin_amdgcn_s_barrier();
    if (t < 14) stage(t + 2);
    __builtin_amdgcn_s_setprio(1);
#pragma unroll
    for (int g = 0; g < 4; ++g)
#pragma unroll
      for (int mi = 0; mi < 8; ++mi)
        acc[mi][g] = __builtin_amdgcn_mfma_f32_16x16x32_bf16(a2[mi], b2[g], acc[mi][g], 0, 0, 0);
    __builtin_amdgcn_s_setprio(0);
  }

  // ---- epilogue: r,z,n + out = h + e*(1-z)*(n-h)
  const int mbase = rb * 256 + wr * 128;
  const int dg = db * 64 + wc * 16 + l15;
  const float b_r = bias[dg];
  const float b_z = bias[DD + dg];
  const float b_i = bias[2 * DD + dg];
  const float b_h = bias[3 * DD + dg];
#pragma unroll
  for (int mi = 0; mi < 8; ++mi) {
#pragma unroll
    for (int j = 0; j < 4; ++j) {
      int m = mbase + mi * 16 + g4 * 4 + j;
      float e = err[m];
      float h = Sf[(size_t)m * DD + dg];
      float r = sigm(acc[mi][0][j] + b_r);
      float z = sigm(acc[mi][1][j] + b_z);
      float n = tanh_fast(acc[mi][2][j] + b_i + r * (acc[mi][3][j] + b_h));
      out[(size_t)m * DD + dg] = h + e * (1.0f - z) * (n - h);
    }
  }
}

extern "C" void kernel_launch(void* const* d_in, const int* in_sizes, int n_in,
                              void* d_out, int out_size, void* d_ws, size_t ws_size,
                              hipStream_t stream) {
  const float* x   = (const float*)d_in[0];
  const float* Wih = (const float*)d_in[1];
  const float* Whh = (const float*)d_in[2];
  const float* bih = (const float*)d_in[3];
  const float* bhh = (const float*)d_in[4];
  const float* We  = (const float*)d_in[5];
  const float* be  = (const float*)d_in[6];
  float* out = (float*)d_out;
  const int M = in_sizes[0] / DD;   // 32768

  char* ws = (char*)d_ws;
  unsigned short* Sb   = (unsigned short*)ws;                              // M*D*2
  unsigned short* Wcat = (unsigned short*)(ws + (size_t)M * DD * 2);       // 8 MB
  float* bias = (float*)(ws + (size_t)M * DD * 2 + (size_t)4 * DD * DD * 2);
  float* err  = (float*)(ws + (size_t)M * DD * 2 + (size_t)4 * DD * DD * 2 + (size_t)4 * DD * 4);

  prep_weights<<<4096, 256, 0, stream>>>(Wih, Whh, bih, bhh, Wcat, bias);

  const int nwg = (M / 256) * (DD / 64);   // 128 * 16 = 2048
  const float* S = x;
  for (int it = 0; it < 2; ++it) {
    error_cast<<<M, 256, 0, stream>>>(S, We, be, Sb, err);
    gru_fused_gemm<<<nwg, 512, 0, stream>>>(Sb, Wcat, bias, err, S, out, M);
    S = out;   // iteration 2: in-place update of d_out (element-local read-before-write)
  }
}